// Round 6
// baseline (279.346 us; speedup 1.0000x reference)
//
#include <hip/hip_runtime.h>

#define H 896
#define NH 14
#define HD 64
#define DFF 4864
#define SEQ 2048
#define NTOK 4096
#define QKVN 1152
// ASCALE * log2(e), folded into q-weights/bias at conversion; softmax in exp2 domain
#define QSCALE 0.1803368801111244f

typedef unsigned short bf16_t;
typedef __attribute__((ext_vector_type(8))) short bf16x8;
typedef __attribute__((ext_vector_type(4))) float f32x4;

#define MFMA16(a, b, c) __builtin_amdgcn_mfma_f32_16x16x32_bf16(a, b, c, 0, 0, 0)

__device__ __forceinline__ unsigned short f2bf(float f) {
  unsigned u = __float_as_uint(f);
  u += 0x7fffu + ((u >> 16) & 1u);   // RNE
  return (unsigned short)(u >> 16);
}

__device__ __forceinline__ float bf2f(unsigned short h) {
  return __uint_as_float((unsigned)h << 16);
}

__device__ __forceinline__ unsigned cvtpk(float lo, float hi) {
  unsigned r;
  asm("v_cvt_pk_bf16_f32 %0, %1, %2" : "=v"(r) : "v"(lo), "v"(hi));
  return r;
}

__device__ __forceinline__ void gload_lds16(const void* g, void* l) {
  __builtin_amdgcn_global_load_lds(
      (const __attribute__((address_space(1))) unsigned int*)g,
      (__attribute__((address_space(3))) unsigned int*)l, 16, 0, 0);
}

// ---------------- fused weight convert f32 -> bf16 ---------------------------
__global__ void cvt_all(const float* __restrict__ q_w, const float* __restrict__ k_w,
                        const float* __restrict__ v_w, const float* __restrict__ o_w,
                        const float* __restrict__ g_w, const float* __restrict__ u_w,
                        const float* __restrict__ dn_w, bf16_t* __restrict__ wqkv,
                        bf16_t* __restrict__ wo, bf16_t* __restrict__ wgu,
                        bf16_t* __restrict__ wd) {
  const int bx = blockIdx.x;
  float sc = 1.f;
  if (bx < 1792) {
    const float* src; bf16_t* dst; int base;
    if (bx < 784)      { src = q_w; dst = wqkv;          base = 0;  sc = QSCALE; }
    else if (bx < 896) { src = k_w; dst = wqkv + 802816; base = 784; }
    else if (bx < 1008){ src = v_w; dst = wqkv + 917504; base = 896; }
    else               { src = o_w; dst = wo;            base = 1008; }
    const int i = ((bx - base) * 256 + threadIdx.x) * 4;
    const float4 v = *(const float4*)(src + i);
    uint2 o;
    o.x = (unsigned)f2bf(v.x * sc) | ((unsigned)f2bf(v.y * sc) << 16);
    o.y = (unsigned)f2bf(v.z * sc) | ((unsigned)f2bf(v.w * sc) << 16);
    *(uint2*)(dst + i) = o;
  } else if (bx < 10304) {
    // merged gate/up, dest-indexed: wgu row r: grp=r>>5, sub=r&31
    const int i = ((bx - 1792) * 256 + threadIdx.x) * 4;
    const unsigned r = (unsigned)i / 896u;
    const int col = i - (int)r * 896;
    const int sub = r & 31;
    const unsigned srow = (r >> 5) * 16 + (sub & 15);
    const float* src = ((sub < 16) ? g_w : u_w) + (size_t)srow * 896 + col;
    const float4 v = *(const float4*)src;
    uint2 o;
    o.x = (unsigned)f2bf(v.x) | ((unsigned)f2bf(v.y) << 16);
    o.y = (unsigned)f2bf(v.z) | ((unsigned)f2bf(v.w) << 16);
    *(uint2*)(wgu + i) = o;
  } else {
    const int i = ((bx - 10304) * 256 + threadIdx.x) * 4;
    const float4 v = *(const float4*)(dn_w + i);
    uint2 o;
    o.x = (unsigned)f2bf(v.x) | ((unsigned)f2bf(v.y) << 16);
    o.y = (unsigned)f2bf(v.z) | ((unsigned)f2bf(v.w) << 16);
    *(uint2*)(wd + i) = o;
  }
}

__global__ void bias_cat_kernel(const float* __restrict__ qb, const float* __restrict__ kb,
                                const float* __restrict__ vb, float* __restrict__ out) {
  const int i = blockIdx.x * 256 + threadIdx.x;
  if (i < 1152)
    out[i] = (i < 896) ? qb[i] * QSCALE : ((i < 1024) ? kb[i - 896] : vb[i - 1024]);
}

// ---------------- RMSNorm: one block per row of 896, f32 in -> bf16 out ------
__global__ __launch_bounds__(256)
void rmsnorm_kernel(const float* __restrict__ x, const float* __restrict__ wt,
                    bf16_t* __restrict__ out) {
  const int row = blockIdx.x;
  const int t = threadIdx.x;
  float4 v = {0.f, 0.f, 0.f, 0.f};
  float ss = 0.f;
  const float4* xr = (const float4*)(x + (size_t)row * H);
  if (t < 224) {
    v = xr[t];
    ss = v.x * v.x + v.y * v.y + v.z * v.z + v.w * v.w;
  }
#pragma unroll
  for (int m = 32; m; m >>= 1) ss += __shfl_xor(ss, m);
  __shared__ float wsum[4];
  if ((t & 63) == 0) wsum[t >> 6] = ss;
  __syncthreads();
  const float rinv = rsqrtf((wsum[0] + wsum[1] + wsum[2] + wsum[3]) * (1.f / 896.f) + 1e-5f);
  if (t < 224) {
    const float4 wv = ((const float4*)wt)[t];
    uint2 o;
    o.x = (unsigned)f2bf(v.x * rinv * wv.x) | ((unsigned)f2bf(v.y * rinv * wv.y) << 16);
    o.y = (unsigned)f2bf(v.z * rinv * wv.z) | ((unsigned)f2bf(v.w * rinv * wv.w) << 16);
    ((uint2*)(out + (size_t)row * H))[t] = o;
  }
}

// ---------------- GEMM out[M][N] = A[M][K'] @ B[N][K']^T ---------------------
// BM x 128 tile, BK=64, 4 waves (2x2). Counted-vmcnt pipelined double-buffer.
template <int BM, int EPI>
__global__ __launch_bounds__(256, BM == 64 ? 3 : 2)
void gemm_bt(const bf16_t* __restrict__ A, const bf16_t* __restrict__ Bw,
             bf16_t* __restrict__ outb, float* __restrict__ outf,
             const float* __restrict__ bias, const float* __restrict__ res,
             int M, int N, int K, int lda, int ldb) {
  __shared__ bf16_t As[2][BM * 64];
  __shared__ bf16_t Bs[2][128 * 64];
  const int tid = threadIdx.x;
  const int lane = tid & 63;
  const int q = lane & 15;
  const int g = lane >> 4;
  const int w = tid >> 6;
  const int wr = w >> 1, wc = w & 1;
  const int local = blockIdx.x >> 3;
  const int xcd = blockIdx.x & 7;
  int m0, n0, kbase = 0;
  size_t pofs = 0;
  if (EPI == 2) {       // split-K decode: local = n*8 + m_l*2 + ks (BM=128)
    const int rem = local & 7;
    m0 = (xcd * 4 + (rem >> 1)) * BM;
    n0 = (local >> 3) * 128;
    kbase = (rem & 1) * K;
    pofs = (size_t)(rem & 1) * M * N;
  } else {
    m0 = (xcd * 8 + (local & 7)) * BM;
    n0 = (local >> 3) * 128;
  }
  const int MREP = BM / 32;
  const int ACH = BM / 32;
  const int NSTEP = K >> 6;

  f32x4 acc[BM / 32][4] = {};

#define STAGE_G(p, step)                                                        \
  {                                                                             \
    const int k0 = kbase + ((step) << 6);                                       \
    _Pragma("unroll") for (int c = 0; c < ACH; ++c) {                           \
      const int e = (c * 256 + tid) * 8;                                        \
      const int r = e >> 6;                                                     \
      const int csw = (e & 63) ^ ((r & 7) << 3);                                \
      gload_lds16(A + (size_t)(m0 + r) * lda + (k0 + csw), As[p] + e);          \
    }                                                                           \
    _Pragma("unroll") for (int c = 0; c < 4; ++c) {                             \
      const int e = (c * 256 + tid) * 8;                                        \
      const int r = e >> 6;                                                     \
      const int csw = (e & 63) ^ ((r & 7) << 3);                                \
      gload_lds16(Bw + (size_t)(n0 + r) * ldb + (k0 + csw), Bs[p] + e);         \
    }                                                                           \
  }

  STAGE_G(0, 0);
  int p = 0;
  for (int step = 0; step < NSTEP; ++step) {
    if (step + 1 < NSTEP) {
      STAGE_G(p ^ 1, step + 1);
      if constexpr (BM == 64) asm volatile("s_waitcnt vmcnt(6)" ::: "memory");
      else                    asm volatile("s_waitcnt vmcnt(8)" ::: "memory");
    } else {
      asm volatile("s_waitcnt vmcnt(0)" ::: "memory");
    }
    __builtin_amdgcn_s_barrier();
    __builtin_amdgcn_sched_barrier(0);
#pragma unroll
    for (int kk = 0; kk < 2; ++kk) {
      const int koff = (kk * 32 + g * 8) ^ ((q & 7) << 3);
      bf16x8 a[BM / 32], b[4];
#pragma unroll
      for (int m = 0; m < MREP; ++m)
        a[m] = *(const bf16x8*)(As[p] + (wr * (BM / 2) + m * 16 + q) * 64 + koff);
#pragma unroll
      for (int n = 0; n < 4; ++n)
        b[n] = *(const bf16x8*)(Bs[p] + (wc * 64 + n * 16 + q) * 64 + koff);
#pragma unroll
      for (int m = 0; m < MREP; ++m)
#pragma unroll
        for (int n = 0; n < 4; ++n)
          acc[m][n] = MFMA16(a[m], b[n], acc[m][n]);
    }
    __builtin_amdgcn_sched_barrier(0);
    __builtin_amdgcn_s_barrier();
    p ^= 1;
  }

#pragma unroll
  for (int m = 0; m < MREP; ++m) {
    const int row = m0 + wr * (BM / 2) + m * 16 + g * 4;
#pragma unroll
    for (int n = 0; n < 4; ++n) {
      const int col = n0 + wc * 64 + n * 16 + q;
      const float bv = (EPI == 0) ? bias[col] : 0.f;
#pragma unroll
      for (int i = 0; i < 4; ++i) {
        const size_t idx = (size_t)(row + i) * N + col;
        if (EPI == 0)      outb[idx] = f2bf(acc[m][n][i] + bv);
        else if (EPI == 1) outf[idx] = acc[m][n][i] + res[idx];
        else               outb[pofs + idx] = f2bf(acc[m][n][i]);
      }
    }
  }
#undef STAGE_G
}

// ---------------- split-K reduce: out += p0 + p1 (bf16 partials) -------------
__global__ __launch_bounds__(256)
void reduce_kernel(float* __restrict__ out, const bf16_t* __restrict__ part) {
  const int i = (blockIdx.x * 256 + threadIdx.x) * 4;
  const ushort4 a = *(const ushort4*)(part + i);
  const ushort4 b = *(const ushort4*)(part + 3670016 + i);
  float4 o = *(float4*)(out + i);
  o.x += bf2f(a.x) + bf2f(b.x);
  o.y += bf2f(a.y) + bf2f(b.y);
  o.z += bf2f(a.z) + bf2f(b.z);
  o.w += bf2f(a.w) + bf2f(b.w);
  *(float4*)(out + i) = o;
}

// ---------------- merged gate/up GEMM v3: 256x256 tile, 8 waves --------------
// BK=32, quad-buffered 128KB dynamic LDS, prefetch distance 2, vmcnt(8),
// ONE barrier per K-step. Wave = 128x64 output (8x4 frags) -> 42.7 FLOP per
// LDS byte read (was 32). Swizzle for BK=32: col ^= ((row>>1)&3)<<3 -> a
// wave's 16-row column read covers all 8 16B slots twice (2-way = free).
// Race ledger: barrier skew <=1 step; step-t writes buf[(t+2)&3], concurrent
// readers use buf[t&3]/buf[(t+1)&3] (disjoint); step t-1 frags consumed by
// MFMA (lgkmcnt) before any wave passes barrier(t).
__global__ __launch_bounds__(512, 2)
void gateup_kernel(const bf16_t* __restrict__ A, const bf16_t* __restrict__ Wgu,
                   bf16_t* __restrict__ gu) {
  extern __shared__ __align__(16) char smem[];
  bf16_t* Abuf = (bf16_t*)smem;              // 4 x 256x32 = 64 KB
  bf16_t* Bbuf = (bf16_t*)(smem + 65536);    // 4 x 256x32 = 64 KB
  const int tid = threadIdx.x;
  const int lane = tid & 63;
  const int q = lane & 15;
  const int g = lane >> 4;
  const int w = tid >> 6;
  const int wr = w >> 2;        // 0..1 (M)
  const int wc = w & 3;         // 0..3 (N)
  const int m0 = (blockIdx.x & 15) * 256;
  const int n0 = (blockIdx.x >> 4) * 256;    // wgu row space

  f32x4 acc[8][4] = {};

#define STAGE_GU(beta, step)                                                    \
  {                                                                             \
    const int k0 = (step) << 5;                                                 \
    _Pragma("unroll") for (int c = 0; c < 2; ++c) {                             \
      const int e = (c * 512 + tid) * 8;                                        \
      const int r = e >> 5;                                                     \
      const int csw = (e & 31) ^ (((r >> 1) & 3) << 3);                         \
      gload_lds16(A + (size_t)(m0 + r) * 896 + (k0 + csw),                      \
                  Abuf + (beta) * 8192 + e);                                    \
      gload_lds16(Wgu + (size_t)(n0 + r) * 896 + (k0 + csw),                    \
                  Bbuf + (beta) * 8192 + e);                                    \
    }                                                                           \
  }

  STAGE_GU(0, 0);
  STAGE_GU(1, 1);
  const int swz = ((q >> 1) & 3) << 3;       // row-swizzle slot, q-dependent only
  for (int t = 0; t < 28; ++t) {
    if (t + 2 < 28) {
      STAGE_GU((t + 2) & 3, t + 2);
      asm volatile("s_waitcnt vmcnt(8)" ::: "memory");
    } else if (t + 1 < 28) {
      asm volatile("s_waitcnt vmcnt(4)" ::: "memory");
    } else {
      asm volatile("s_waitcnt vmcnt(0)" ::: "memory");
    }
    __builtin_amdgcn_s_barrier();
    __builtin_amdgcn_sched_barrier(0);
    const bf16_t* At = Abuf + (t & 3) * 8192;
    const bf16_t* Bt = Bbuf + (t & 3) * 8192;
    const int koff = (g * 8) ^ swz;
    bf16x8 a[8], b[4];
#pragma unroll
    for (int m = 0; m < 8; ++m)
      a[m] = *(const bf16x8*)(At + (wr * 128 + m * 16 + q) * 32 + koff);
#pragma unroll
    for (int n = 0; n < 4; ++n)
      b[n] = *(const bf16x8*)(Bt + (wc * 64 + n * 16 + q) * 32 + koff);
    __builtin_amdgcn_s_setprio(1);
#pragma unroll
    for (int m = 0; m < 8; ++m)
#pragma unroll
      for (int n = 0; n < 4; ++n)
        acc[m][n] = MFMA16(a[m], b[n], acc[m][n]);
    __builtin_amdgcn_s_setprio(0);
  }

  // epilogue: frag pairs (n=0,1)/(n=2,3) are gate/up for the same dff rows
#pragma unroll
  for (int m = 0; m < 8; ++m) {
    const int row = m0 + wr * 128 + m * 16 + g * 4;
#pragma unroll
    for (int pr = 0; pr < 2; ++pr) {
      const int dff = (n0 >> 1) + wc * 32 + pr * 16 + q;
#pragma unroll
      for (int i = 0; i < 4; ++i) {
        const float gv = acc[m][2 * pr][i];
        const float uv = acc[m][2 * pr + 1][i];
        const float r = (gv / (1.f + __expf(-gv))) * uv;
        gu[(size_t)(row + i) * DFF + dff] = f2bf(r);
      }
    }
  }
#undef STAGE_GU
}

// ---------------- flash attention v3: swapped QK^T, lane-local softmax -------
__global__ __launch_bounds__(512, 4)
void attn_kernel(const bf16_t* __restrict__ qkv, bf16_t* __restrict__ attn_out) {
  __shared__ __align__(16) char asmem[32768];
  bf16_t* lds_k = (bf16_t*)asmem;          // 16 KB: Q tile, then K tiles
  char* lds_v = asmem + 16384;             // 16 KB: V^T
  const int tid = threadIdx.x;
  const int lane = tid & 63;
  const int q = lane & 15;
  const int g = lane >> 4;
  const int w = tid >> 6;
  const int qt = blockIdx.x;
  const int h = blockIdx.y;
  const int b = blockIdx.z;
  const int kvh = h / 7;
  const char* Qg = (const char*)(qkv + (size_t)(b * SEQ + qt * 128) * QKVN + h * HD);
  const char* Kg = (const char*)(qkv + (size_t)(b * SEQ) * QKVN + H + kvh * HD);
  const char* Vg = (const char*)(qkv + (size_t)(b * SEQ) * QKVN + 1024 + kvh * HD);

#pragma unroll
  for (int c = 0; c < 2; ++c) {
    const int e = (c * 512 + tid) * 8;
    const int tok = e >> 6;
    const int sb = ((e & 63) * 2) ^ ((tok & 7) << 4);
    gload_lds16(Qg + (size_t)tok * 2304 + sb, lds_k + e);
  }
  __syncthreads();
  bf16x8 aq[2];
  {
    const int qrow = w * 16 + q;
#pragma unroll
    for (int kk = 0; kk < 2; ++kk) {
      const int sb = ((kk * 32 + g * 8) * 2) ^ ((qrow & 7) << 4);
      aq[kk] = *(const bf16x8*)((const char*)lds_k + qrow * 128 + sb);
    }
  }

  const int vtok = (w & 1) * 64 + lane;
  const int vdg = w >> 1;

  bf16x8 vcur[2], vnxt[2];
#pragma unroll
  for (int j = 0; j < 2; ++j)
    vcur[j] = *(const bf16x8*)(Vg + (size_t)vtok * 2304 + (size_t)(vdg * 16 + j * 8) * 2);

  float m_run = -1.0e30f, l_run = 0.f;
  f32x4 acc[4] = {};

  for (int kt = 0; kt < 16; ++kt) {
    __syncthreads();
#pragma unroll
    for (int c = 0; c < 2; ++c) {
      const int e = (c * 512 + tid) * 8;
      const int row = e >> 6;
      const int kvp = 32 * (row >> 5) + 8 * ((row >> 2) & 3) + 4 * ((row >> 4) & 1) + (row & 3);
      const int sb = ((e & 63) * 2) ^ ((row & 7) << 4);
      gload_lds16(Kg + (size_t)(kt * 128 + kvp) * 2304 + sb, lds_k + e);
    }
    if (kt < 15) {
#pragma unroll
      for (int j = 0; j < 2; ++j)
        vnxt[j] = *(const bf16x8*)(Vg + (size_t)((kt + 1) * 128 + vtok) * 2304 +
                                   (size_t)(vdg * 16 + j * 8) * 2);
    }
#pragma unroll
    for (int j = 0; j < 2; ++j) {
      const unsigned short* pv = (const unsigned short*)&vcur[j];
#pragma unroll
      for (int u = 0; u < 8; ++u) {
        const int d = vdg * 16 + j * 8 + u;
        const int by = (d << 8) + (vtok << 1);
        *(unsigned short*)(lds_v + (by ^ ((d & 7) << 4))) = pv[u];
      }
    }
    __syncthreads();

    f32x4 s[8] = {};
#pragma unroll
    for (int kk = 0; kk < 2; ++kk) {
      const int sb = ((kk * 32 + g * 8) * 2) ^ ((q & 7) << 4);
      __builtin_amdgcn_s_setprio(1);
#pragma unroll
      for (int f = 0; f < 8; ++f) {
        const bf16x8 ak = *(const bf16x8*)((const char*)lds_k + (f * 16 + q) * 128 + sb);
        s[f] = MFMA16(ak, aq[kk], s[f]);
      }
      __builtin_amdgcn_s_setprio(0);
    }

    {
      f32x4 vm = s[0];
#pragma unroll
      for (int f = 1; f < 8; ++f) {
#pragma unroll
        for (int i = 0; i < 4; ++i) vm[i] = fmaxf(vm[i], s[f][i]);
      }
      float mx = fmaxf(fmaxf(vm[0], vm[1]), fmaxf(vm[2], vm[3]));
      mx = fmaxf(mx, __shfl_xor(mx, 16));
      mx = fmaxf(mx, __shfl_xor(mx, 32));
      if (!__all(mx <= m_run + 11.5f)) {
        const float mnew = fmaxf(m_run, mx);
        const float corr = exp2f(m_run - mnew);
        m_run = mnew;
        l_run *= corr;
#pragma unroll
        for (int n = 0; n < 4; ++n)
#pragma unroll
          for (int i = 0; i < 4; ++i) acc[n][i] *= corr;
      }
      f32x4 vs = {0.f, 0.f, 0.f, 0.f};
#pragma unroll
      for (int f = 0; f < 8; ++f)
#pragma unroll
        for (int i = 0; i < 4; ++i) {
          const float p = exp2f(s[f][i] - m_run);
          s[f][i] = p;
          vs[i] += p;
        }
      l_run += (vs[0] + vs[1]) + (vs[2] + vs[3]);
    }

    unsigned pk[8][2];
#pragma unroll
    for (int f = 0; f < 8; ++f) {
      pk[f][0] = cvtpk(s[f][0], s[f][1]);
      pk[f][1] = cvtpk(s[f][2], s[f][3]);
    }

#pragma unroll
    for (int st = 0; st < 4; ++st) {
      union { bf16x8 v; unsigned u[4]; } bp;
      bp.u[0] = pk[2 * st][0];
      bp.u[1] = pk[2 * st][1];
      bp.u[2] = pk[2 * st + 1][0];
      bp.u[3] = pk[2 * st + 1][1];
      const int cb = (st * 32 + g * 8) * 2;
      bf16x8 bv[4];
#pragma unroll
      for (int n = 0; n < 4; ++n) {
        const int d = n * 16 + q;
        bv[n] = *(const bf16x8*)(lds_v + d * 256 + (cb ^ ((d & 7) << 4)));
      }
      __builtin_amdgcn_s_setprio(1);
#pragma unroll
      for (int n = 0; n < 4; ++n)
        acc[n] = MFMA16(bv[n], bp.v, acc[n]);
      __builtin_amdgcn_s_setprio(0);
    }
    vcur[0] = vnxt[0];
    vcur[1] = vnxt[1];
  }

  l_run += __shfl_xor(l_run, 16);
  l_run += __shfl_xor(l_run, 32);
  const float rl = 1.f / l_run;

  __syncthreads();
  {
    char* lds_o = asmem;
    const int row = w * 16 + q;
#pragma unroll
    for (int n = 0; n < 4; ++n)
#pragma unroll
      for (int i2 = 0; i2 < 2; ++i2) {
        const unsigned pr = cvtpk(acc[n][2 * i2] * rl, acc[n][2 * i2 + 1] * rl);
        *(unsigned*)(lds_o + row * 144 + n * 32 + g * 8 + i2 * 4) = pr;
      }
  }
  __syncthreads();
  {
    const char* lds_o = asmem;
    const int row2 = tid >> 2;
    const int seg = tid & 3;
    const uint4 v0 = *(const uint4*)(lds_o + row2 * 144 + seg * 32);
    const uint4 v1 = *(const uint4*)(lds_o + row2 * 144 + seg * 32 + 16);
    bf16_t* dst = attn_out + ((size_t)(b * SEQ + qt * 128 + row2)) * H + h * HD + seg * 16;
    *(uint4*)dst = v0;
    *(uint4*)(dst + 8) = v1;
  }
}

// ---------------- launcher ---------------------------------------------------
extern "C" void kernel_launch(void* const* d_in, const int* in_sizes, int n_in,
                              void* d_out, int out_size, void* d_ws, size_t ws_size,
                              hipStream_t stream) {
  const float* x    = (const float*)d_in[0];
  const float* ln1w = (const float*)d_in[3];
  const float* q_w  = (const float*)d_in[4];
  const float* q_b  = (const float*)d_in[5];
  const float* k_w  = (const float*)d_in[6];
  const float* k_b  = (const float*)d_in[7];
  const float* v_w  = (const float*)d_in[8];
  const float* v_b  = (const float*)d_in[9];
  const float* o_w  = (const float*)d_in[10];
  const float* ln2w = (const float*)d_in[11];
  const float* g_w  = (const float*)d_in[12];
  const float* u_w  = (const float*)d_in[13];
  const float* dn_w = (const float*)d_in[14];
  float* out = (float*)d_out;

  char* ws = (char*)d_ws;
  bf16_t* wqkv = (bf16_t*)(ws + 0);         // 1152x896
  bf16_t* wo   = (bf16_t*)(ws + 2064384);   // 896x896
  bf16_t* wgu  = (bf16_t*)(ws + 3670016);   // 9728x896 (interleaved gate/up)
  bf16_t* wd   = (bf16_t*)(ws + 21102592);  // 896x4864
  float*  bqkv = (float*)(ws + 29818880);   // 1152
  bf16_t* hbuf = (bf16_t*)(ws + 29823488);  // 4096x896 (h1, then h2)
  bf16_t* qkv  = (bf16_t*)(ws + 37163520);  // 4096x1152
  bf16_t* attn = (bf16_t*)(ws + 46600704);  // 4096x896
  bf16_t* gu   = (bf16_t*)(ws + 53940736);  // 4096x4864
  // split-K partials (bf16, 2x 4096x896) overlay dead bqkv/hbuf/qkv region
  bf16_t* part = (bf16_t*)(ws + 29818880);  // [29818880, 44498944)

  static int gu_attr_set = 0;
  if (!gu_attr_set) {
    hipFuncSetAttribute((const void*)gateup_kernel,
                        hipFuncAttributeMaxDynamicSharedMemorySize, 131072);
    gu_attr_set = 1;
  }

  cvt_all<<<14560, 256, 0, stream>>>(q_w, k_w, v_w, o_w, g_w, u_w, dn_w,
                                     wqkv, wo, wgu, wd);
  bias_cat_kernel<<<5, 256, 0, stream>>>(q_b, k_b, v_b, bqkv);

  // pre-norm attention
  rmsnorm_kernel<<<4096, 256, 0, stream>>>(x, ln1w, hbuf);
  gemm_bt<64, 0><<<576, 256, 0, stream>>>(hbuf, wqkv, qkv, nullptr, bqkv,
                                          nullptr, 4096, 1152, 896, 896, 896);
  attn_kernel<<<dim3(16, 14, 2), 512, 0, stream>>>(qkv, attn);
  gemm_bt<64, 1><<<448, 256, 0, stream>>>(attn, wo, nullptr, out, nullptr, x,
                                          4096, 896, 896, 896, 896);
  // pre-norm SwiGLU MLP
  rmsnorm_kernel<<<4096, 256, 0, stream>>>(out, ln2w, hbuf);
  gateup_kernel<<<608, 512, 131072, stream>>>(hbuf, wgu, gu);
  // down-proj: split-K=2 bf16 partials + fused reduce(+residual)
  gemm_bt<128, 2><<<448, 256, 0, stream>>>(gu, wd, part, nullptr, nullptr, nullptr,
                                           4096, 896, 2432, 4864, 4864);
  reduce_kernel<<<3584, 256, 0, stream>>>(out, part);
}

// Round 8
// 272.295 us; speedup vs baseline: 1.0259x; 1.0259x over previous
//
#include <hip/hip_runtime.h>

#define H 896
#define NH 14
#define HD 64
#define DFF 4864
#define SEQ 2048
#define NTOK 4096
#define QKVN 1152
// ASCALE * log2(e), folded into q-weights/bias at conversion; softmax in exp2 domain
#define QSCALE 0.1803368801111244f

typedef unsigned short bf16_t;
typedef __attribute__((ext_vector_type(8))) short bf16x8;
typedef __attribute__((ext_vector_type(4))) float f32x4;

#define MFMA16(a, b, c) __builtin_amdgcn_mfma_f32_16x16x32_bf16(a, b, c, 0, 0, 0)

__device__ __forceinline__ unsigned short f2bf(float f) {
  unsigned u = __float_as_uint(f);
  u += 0x7fffu + ((u >> 16) & 1u);   // RNE
  return (unsigned short)(u >> 16);
}

__device__ __forceinline__ float bf2f(unsigned short h) {
  return __uint_as_float((unsigned)h << 16);
}

__device__ __forceinline__ unsigned cvtpk(float lo, float hi) {
  unsigned r;
  asm("v_cvt_pk_bf16_f32 %0, %1, %2" : "=v"(r) : "v"(lo), "v"(hi));
  return r;
}

__device__ __forceinline__ void gload_lds16(const void* g, void* l) {
  __builtin_amdgcn_global_load_lds(
      (const __attribute__((address_space(1))) unsigned int*)g,
      (__attribute__((address_space(3))) unsigned int*)l, 16, 0, 0);
}

// ---------------- fused weight convert f32 -> bf16 ---------------------------
__global__ void cvt_all(const float* __restrict__ q_w, const float* __restrict__ k_w,
                        const float* __restrict__ v_w, const float* __restrict__ o_w,
                        const float* __restrict__ g_w, const float* __restrict__ u_w,
                        const float* __restrict__ dn_w, bf16_t* __restrict__ wqkv,
                        bf16_t* __restrict__ wo, bf16_t* __restrict__ wgu,
                        bf16_t* __restrict__ wd) {
  const int bx = blockIdx.x;
  float sc = 1.f;
  if (bx < 1792) {
    const float* src; bf16_t* dst; int base;
    if (bx < 784)      { src = q_w; dst = wqkv;          base = 0;  sc = QSCALE; }
    else if (bx < 896) { src = k_w; dst = wqkv + 802816; base = 784; }
    else if (bx < 1008){ src = v_w; dst = wqkv + 917504; base = 896; }
    else               { src = o_w; dst = wo;            base = 1008; }
    const int i = ((bx - base) * 256 + threadIdx.x) * 4;
    const float4 v = *(const float4*)(src + i);
    uint2 o;
    o.x = (unsigned)f2bf(v.x * sc) | ((unsigned)f2bf(v.y * sc) << 16);
    o.y = (unsigned)f2bf(v.z * sc) | ((unsigned)f2bf(v.w * sc) << 16);
    *(uint2*)(dst + i) = o;
  } else if (bx < 10304) {
    // merged gate/up, dest-indexed: wgu row r: grp=r>>5, sub=r&31
    const int i = ((bx - 1792) * 256 + threadIdx.x) * 4;
    const unsigned r = (unsigned)i / 896u;
    const int col = i - (int)r * 896;
    const int sub = r & 31;
    const unsigned srow = (r >> 5) * 16 + (sub & 15);
    const float* src = ((sub < 16) ? g_w : u_w) + (size_t)srow * 896 + col;
    const float4 v = *(const float4*)src;
    uint2 o;
    o.x = (unsigned)f2bf(v.x) | ((unsigned)f2bf(v.y) << 16);
    o.y = (unsigned)f2bf(v.z) | ((unsigned)f2bf(v.w) << 16);
    *(uint2*)(wgu + i) = o;
  } else {
    const int i = ((bx - 10304) * 256 + threadIdx.x) * 4;
    const float4 v = *(const float4*)(dn_w + i);
    uint2 o;
    o.x = (unsigned)f2bf(v.x) | ((unsigned)f2bf(v.y) << 16);
    o.y = (unsigned)f2bf(v.z) | ((unsigned)f2bf(v.w) << 16);
    *(uint2*)(wd + i) = o;
  }
}

__global__ void bias_cat_kernel(const float* __restrict__ qb, const float* __restrict__ kb,
                                const float* __restrict__ vb, float* __restrict__ out) {
  const int i = blockIdx.x * 256 + threadIdx.x;
  if (i < 1152)
    out[i] = (i < 896) ? qb[i] * QSCALE : ((i < 1024) ? kb[i - 896] : vb[i - 1024]);
}

// ---------------- RMSNorm: one block per row of 896, f32 in -> bf16 out ------
__global__ __launch_bounds__(256)
void rmsnorm_kernel(const float* __restrict__ x, const float* __restrict__ wt,
                    bf16_t* __restrict__ out) {
  const int row = blockIdx.x;
  const int t = threadIdx.x;
  float4 v = {0.f, 0.f, 0.f, 0.f};
  float ss = 0.f;
  const float4* xr = (const float4*)(x + (size_t)row * H);
  if (t < 224) {
    v = xr[t];
    ss = v.x * v.x + v.y * v.y + v.z * v.z + v.w * v.w;
  }
#pragma unroll
  for (int m = 32; m; m >>= 1) ss += __shfl_xor(ss, m);
  __shared__ float wsum[4];
  if ((t & 63) == 0) wsum[t >> 6] = ss;
  __syncthreads();
  const float rinv = rsqrtf((wsum[0] + wsum[1] + wsum[2] + wsum[3]) * (1.f / 896.f) + 1e-5f);
  if (t < 224) {
    const float4 wv = ((const float4*)wt)[t];
    uint2 o;
    o.x = (unsigned)f2bf(v.x * rinv * wv.x) | ((unsigned)f2bf(v.y * rinv * wv.y) << 16);
    o.y = (unsigned)f2bf(v.z * rinv * wv.z) | ((unsigned)f2bf(v.w * rinv * wv.w) << 16);
    ((uint2*)(out + (size_t)row * H))[t] = o;
  }
}

// ---------------- GEMM out[M][N] = A[M][K'] @ B[N][K']^T ---------------------
// BM x 128 tile, BK=64, 4 waves (2x2). Counted-vmcnt pipelined double-buffer.
template <int BM, int EPI>
__global__ __launch_bounds__(256, BM == 64 ? 3 : 2)
void gemm_bt(const bf16_t* __restrict__ A, const bf16_t* __restrict__ Bw,
             bf16_t* __restrict__ outb, float* __restrict__ outf,
             const float* __restrict__ bias, const float* __restrict__ res,
             int M, int N, int K, int lda, int ldb) {
  __shared__ bf16_t As[2][BM * 64];
  __shared__ bf16_t Bs[2][128 * 64];
  const int tid = threadIdx.x;
  const int lane = tid & 63;
  const int q = lane & 15;
  const int g = lane >> 4;
  const int w = tid >> 6;
  const int wr = w >> 1, wc = w & 1;
  const int local = blockIdx.x >> 3;
  const int xcd = blockIdx.x & 7;
  int m0, n0, kbase = 0;
  size_t pofs = 0;
  if (EPI == 2) {       // split-K decode: local = n*8 + m_l*2 + ks (BM=128)
    const int rem = local & 7;
    m0 = (xcd * 4 + (rem >> 1)) * BM;
    n0 = (local >> 3) * 128;
    kbase = (rem & 1) * K;
    pofs = (size_t)(rem & 1) * M * N;
  } else {
    m0 = (xcd * 8 + (local & 7)) * BM;
    n0 = (local >> 3) * 128;
  }
  const int MREP = BM / 32;
  const int ACH = BM / 32;
  const int NSTEP = K >> 6;

  f32x4 acc[BM / 32][4] = {};

#define STAGE_G(p, step)                                                        \
  {                                                                             \
    const int k0 = kbase + ((step) << 6);                                       \
    _Pragma("unroll") for (int c = 0; c < ACH; ++c) {                           \
      const int e = (c * 256 + tid) * 8;                                        \
      const int r = e >> 6;                                                     \
      const int csw = (e & 63) ^ ((r & 7) << 3);                                \
      gload_lds16(A + (size_t)(m0 + r) * lda + (k0 + csw), As[p] + e);          \
    }                                                                           \
    _Pragma("unroll") for (int c = 0; c < 4; ++c) {                             \
      const int e = (c * 256 + tid) * 8;                                        \
      const int r = e >> 6;                                                     \
      const int csw = (e & 63) ^ ((r & 7) << 3);                                \
      gload_lds16(Bw + (size_t)(n0 + r) * ldb + (k0 + csw), Bs[p] + e);         \
    }                                                                           \
  }

  STAGE_G(0, 0);
  int p = 0;
  for (int step = 0; step < NSTEP; ++step) {
    if (step + 1 < NSTEP) {
      STAGE_G(p ^ 1, step + 1);
      if constexpr (BM == 64) asm volatile("s_waitcnt vmcnt(6)" ::: "memory");
      else                    asm volatile("s_waitcnt vmcnt(8)" ::: "memory");
    } else {
      asm volatile("s_waitcnt vmcnt(0)" ::: "memory");
    }
    __builtin_amdgcn_s_barrier();
    __builtin_amdgcn_sched_barrier(0);
#pragma unroll
    for (int kk = 0; kk < 2; ++kk) {
      const int koff = (kk * 32 + g * 8) ^ ((q & 7) << 3);
      bf16x8 a[BM / 32], b[4];
#pragma unroll
      for (int m = 0; m < MREP; ++m)
        a[m] = *(const bf16x8*)(As[p] + (wr * (BM / 2) + m * 16 + q) * 64 + koff);
#pragma unroll
      for (int n = 0; n < 4; ++n)
        b[n] = *(const bf16x8*)(Bs[p] + (wc * 64 + n * 16 + q) * 64 + koff);
#pragma unroll
      for (int m = 0; m < MREP; ++m)
#pragma unroll
        for (int n = 0; n < 4; ++n)
          acc[m][n] = MFMA16(a[m], b[n], acc[m][n]);
    }
    __builtin_amdgcn_sched_barrier(0);
    __builtin_amdgcn_s_barrier();
    p ^= 1;
  }

#pragma unroll
  for (int m = 0; m < MREP; ++m) {
    const int row = m0 + wr * (BM / 2) + m * 16 + g * 4;
#pragma unroll
    for (int n = 0; n < 4; ++n) {
      const int col = n0 + wc * 64 + n * 16 + q;
      const float bv = (EPI == 0) ? bias[col] : 0.f;
#pragma unroll
      for (int i = 0; i < 4; ++i) {
        const size_t idx = (size_t)(row + i) * N + col;
        if (EPI == 0)      outb[idx] = f2bf(acc[m][n][i] + bv);
        else if (EPI == 1) outf[idx] = acc[m][n][i] + res[idx];
        else               outb[pofs + idx] = f2bf(acc[m][n][i]);
      }
    }
  }
#undef STAGE_G
}

// ---------------- split-K reduce: out += p0 + p1 (bf16 partials) -------------
__global__ __launch_bounds__(256)
void reduce_kernel(float* __restrict__ out, const bf16_t* __restrict__ part) {
  const int i = (blockIdx.x * 256 + threadIdx.x) * 4;
  const ushort4 a = *(const ushort4*)(part + i);
  const ushort4 b = *(const ushort4*)(part + 3670016 + i);
  float4 o = *(float4*)(out + i);
  o.x += bf2f(a.x) + bf2f(b.x);
  o.y += bf2f(a.y) + bf2f(b.y);
  o.z += bf2f(a.z) + bf2f(b.z);
  o.w += bf2f(a.w) + bf2f(b.w);
  *(float4*)(out + i) = o;
}

// ---------------- merged gate/up GEMM v4: 256x256 tile, 8-phase schedule -----
// 8 waves (2m x 4n), wave = 128x64 output, BK=64, K = 14 tiles (896/64).
// LDS = 8 half-tile slots x 16KB. Per phase: {ds_read subtile || stage 1
// half-tile -> barrier -> lgkmcnt(0) -> setprio(1) -> 16 MFMA -> setprio(0)
// -> barrier}. Counted vmcnt(4) only at phases 3/7 (T3+T4). b-frags read once
// per K-tile at quadrant 0, held in regs. Stage schedule (iter i computes
// tiles 2i/2i+1): ph0:A0d1(2i+1) ph1:A1d1(2i+1) ph2:B0d0(2i+2) ph3:B1d0+vm
// ph4:A0d0(2i+2) ph5:A1d0(2i+2) ph6:B0d1(2i+3) ph7:B1d1(2i+3)+vm.
// Tail prefetches clamp to tile 13 (target slots already free, data unused).
__global__ __launch_bounds__(512, 2)
void gateup_kernel(const bf16_t* __restrict__ A, const bf16_t* __restrict__ Wgu,
                   bf16_t* __restrict__ gu) {
  extern __shared__ __align__(16) char smem[];
  // slots (16KB each): A: d*2+h (0..3); B: 4+d*2+h (4..7)
  const int tid = threadIdx.x;
  const int lane = tid & 63;
  const int q = lane & 15;
  const int g = lane >> 4;
  const int w = tid >> 6;
  const int wr = w >> 2;        // 0..1 (M half)
  const int wc = w & 3;         // 0..3 (N quarter)
  const int m0 = (blockIdx.x & 15) * 256;
  const int n0 = (blockIdx.x >> 4) * 256;    // wgu row space

  f32x4 acc[8][4] = {};
  bf16x8 bq[2][4];
  const int kc0 = ((g * 8) ^ ((q & 7) << 3)) * 2;        // byte col, kk=0
  const int kc1 = ((32 + g * 8) ^ ((q & 7) << 3)) * 2;   // byte col, kk=1
  const char* aBase = smem + wr * 16384 + q * 128;            // + d*32768 + mi*2048
  const char* bBase = smem + 65536 + (wc >> 1) * 16384 +
                      ((wc & 1) * 64 + q) * 128;              // + d*32768 + n*2048

#define STG(slot, P, rbase, kt_)                                                \
  {                                                                             \
    const int ktc = (kt_) < 14 ? (kt_) : 13;                                    \
    const int k0 = ktc << 6;                                                    \
    _Pragma("unroll") for (int c = 0; c < 2; ++c) {                             \
      const int e = (c * 512 + tid) * 8;                                        \
      const int r = e >> 6;                                                     \
      const int csw = (e & 63) ^ ((r & 7) << 3);                                \
      gload_lds16(P + (size_t)((rbase) + r) * 896 + k0 + csw,                   \
                  (bf16_t*)(smem + (slot) * 16384) + e);                        \
    }                                                                           \
  }

#define PH(d, p, STMT, VM)                                                      \
  {                                                                             \
    const char* ab = aBase + (d) * 32768;                                       \
    bf16x8 a0 = *(const bf16x8*)(ab + (2 * (p)) * 2048 + kc0);                  \
    bf16x8 a1 = *(const bf16x8*)(ab + (2 * (p)) * 2048 + kc1);                  \
    bf16x8 a2 = *(const bf16x8*)(ab + (2 * (p) + 1) * 2048 + kc0);              \
    bf16x8 a3 = *(const bf16x8*)(ab + (2 * (p) + 1) * 2048 + kc1);              \
    if ((p) == 0) {                                                             \
      const char* bb = bBase + (d) * 32768;                                     \
      _Pragma("unroll") for (int n = 0; n < 4; ++n) {                           \
        bq[0][n] = *(const bf16x8*)(bb + n * 2048 + kc0);                       \
        bq[1][n] = *(const bf16x8*)(bb + n * 2048 + kc1);                       \
      }                                                                         \
    }                                                                           \
    STMT;                                                                       \
    if (VM) asm volatile("s_waitcnt vmcnt(4)" ::: "memory");                    \
    __builtin_amdgcn_s_barrier();                                               \
    asm volatile("s_waitcnt lgkmcnt(0)" ::: "memory");                          \
    __builtin_amdgcn_sched_barrier(0);                                          \
    __builtin_amdgcn_s_setprio(1);                                              \
    _Pragma("unroll") for (int n = 0; n < 4; ++n)                               \
      acc[2 * (p)][n] = MFMA16(a0, bq[0][n], acc[2 * (p)][n]);                  \
    _Pragma("unroll") for (int n = 0; n < 4; ++n)                               \
      acc[2 * (p) + 1][n] = MFMA16(a2, bq[0][n], acc[2 * (p) + 1][n]);          \
    _Pragma("unroll") for (int n = 0; n < 4; ++n)                               \
      acc[2 * (p)][n] = MFMA16(a1, bq[1][n], acc[2 * (p)][n]);                  \
    _Pragma("unroll") for (int n = 0; n < 4; ++n)                               \
      acc[2 * (p) + 1][n] = MFMA16(a3, bq[1][n], acc[2 * (p) + 1][n]);          \
    __builtin_amdgcn_s_setprio(0);                                              \
    __builtin_amdgcn_s_barrier();                                               \
  }

  // prologue: tile0 (A+B, d0) + tile1 B (d1); vmcnt(4) -> tile0 landed
  STG(0, A, m0, 0);
  STG(1, A, m0 + 128, 0);
  STG(4, Wgu, n0, 0);
  STG(5, Wgu, n0 + 128, 0);
  STG(6, Wgu, n0, 1);
  STG(7, Wgu, n0 + 128, 1);
  asm volatile("s_waitcnt vmcnt(4)" ::: "memory");
  __builtin_amdgcn_s_barrier();

  for (int i = 0; i < 7; ++i) {            // 7 iters x 2 tiles = 14 K-tiles
    const int t2 = 2 * i;
    PH(0, 0, STG(2, A, m0, t2 + 1), 0);
    PH(0, 1, STG(3, A, m0 + 128, t2 + 1), 0);
    PH(0, 2, STG(4, Wgu, n0, t2 + 2), 0);
    PH(0, 3, STG(5, Wgu, n0 + 128, t2 + 2), 1);
    PH(1, 0, STG(0, A, m0, t2 + 2), 0);
    PH(1, 1, STG(1, A, m0 + 128, t2 + 2), 0);
    PH(1, 2, STG(6, Wgu, n0, t2 + 3), 0);
    PH(1, 3, STG(7, Wgu, n0 + 128, t2 + 3), 1);
  }

  // epilogue: frag pairs (n=0,1)/(n=2,3) are gate/up for the same dff rows
#pragma unroll
  for (int m = 0; m < 8; ++m) {
    const int row = m0 + wr * 128 + m * 16 + g * 4;
#pragma unroll
    for (int pr = 0; pr < 2; ++pr) {
      const int dff = (n0 >> 1) + wc * 32 + pr * 16 + q;
#pragma unroll
      for (int i = 0; i < 4; ++i) {
        const float gv = acc[m][2 * pr][i];
        const float uv = acc[m][2 * pr + 1][i];
        const float r = (gv / (1.f + __expf(-gv))) * uv;
        gu[(size_t)(row + i) * DFF + dff] = f2bf(r);
      }
    }
  }
#undef STG
#undef PH
}

// ---------------- flash attention v3: swapped QK^T, lane-local softmax -------
__global__ __launch_bounds__(512, 4)
void attn_kernel(const bf16_t* __restrict__ qkv, bf16_t* __restrict__ attn_out) {
  __shared__ __align__(16) char asmem[32768];
  bf16_t* lds_k = (bf16_t*)asmem;          // 16 KB: Q tile, then K tiles
  char* lds_v = asmem + 16384;             // 16 KB: V^T
  const int tid = threadIdx.x;
  const int lane = tid & 63;
  const int q = lane & 15;
  const int g = lane >> 4;
  const int w = tid >> 6;
  const int qt = blockIdx.x;
  const int h = blockIdx.y;
  const int b = blockIdx.z;
  const int kvh = h / 7;
  const char* Qg = (const char*)(qkv + (size_t)(b * SEQ + qt * 128) * QKVN + h * HD);
  const char* Kg = (const char*)(qkv + (size_t)(b * SEQ) * QKVN + H + kvh * HD);
  const char* Vg = (const char*)(qkv + (size_t)(b * SEQ) * QKVN + 1024 + kvh * HD);

#pragma unroll
  for (int c = 0; c < 2; ++c) {
    const int e = (c * 512 + tid) * 8;
    const int tok = e >> 6;
    const int sb = ((e & 63) * 2) ^ ((tok & 7) << 4);
    gload_lds16(Qg + (size_t)tok * 2304 + sb, lds_k + e);
  }
  __syncthreads();
  bf16x8 aq[2];
  {
    const int qrow = w * 16 + q;
#pragma unroll
    for (int kk = 0; kk < 2; ++kk) {
      const int sb = ((kk * 32 + g * 8) * 2) ^ ((qrow & 7) << 4);
      aq[kk] = *(const bf16x8*)((const char*)lds_k + qrow * 128 + sb);
    }
  }

  const int vtok = (w & 1) * 64 + lane;
  const int vdg = w >> 1;

  bf16x8 vcur[2], vnxt[2];
#pragma unroll
  for (int j = 0; j < 2; ++j)
    vcur[j] = *(const bf16x8*)(Vg + (size_t)vtok * 2304 + (size_t)(vdg * 16 + j * 8) * 2);

  float m_run = -1.0e30f, l_run = 0.f;
  f32x4 acc[4] = {};

  for (int kt = 0; kt < 16; ++kt) {
    __syncthreads();
#pragma unroll
    for (int c = 0; c < 2; ++c) {
      const int e = (c * 512 + tid) * 8;
      const int row = e >> 6;
      const int kvp = 32 * (row >> 5) + 8 * ((row >> 2) & 3) + 4 * ((row >> 4) & 1) + (row & 3);
      const int sb = ((e & 63) * 2) ^ ((row & 7) << 4);
      gload_lds16(Kg + (size_t)(kt * 128 + kvp) * 2304 + sb, lds_k + e);
    }
    if (kt < 15) {
#pragma unroll
      for (int j = 0; j < 2; ++j)
        vnxt[j] = *(const bf16x8*)(Vg + (size_t)((kt + 1) * 128 + vtok) * 2304 +
                                   (size_t)(vdg * 16 + j * 8) * 2);
    }
#pragma unroll
    for (int j = 0; j < 2; ++j) {
      const unsigned short* pv = (const unsigned short*)&vcur[j];
#pragma unroll
      for (int u = 0; u < 8; ++u) {
        const int d = vdg * 16 + j * 8 + u;
        const int by = (d << 8) + (vtok << 1);
        *(unsigned short*)(lds_v + (by ^ ((d & 7) << 4))) = pv[u];
      }
    }
    __syncthreads();

    f32x4 s[8] = {};
#pragma unroll
    for (int kk = 0; kk < 2; ++kk) {
      const int sb = ((kk * 32 + g * 8) * 2) ^ ((q & 7) << 4);
      __builtin_amdgcn_s_setprio(1);
#pragma unroll
      for (int f = 0; f < 8; ++f) {
        const bf16x8 ak = *(const bf16x8*)((const char*)lds_k + (f * 16 + q) * 128 + sb);
        s[f] = MFMA16(ak, aq[kk], s[f]);
      }
      __builtin_amdgcn_s_setprio(0);
    }

    {
      f32x4 vm = s[0];
#pragma unroll
      for (int f = 1; f < 8; ++f) {
#pragma unroll
        for (int i = 0; i < 4; ++i) vm[i] = fmaxf(vm[i], s[f][i]);
      }
      float mx = fmaxf(fmaxf(vm[0], vm[1]), fmaxf(vm[2], vm[3]));
      mx = fmaxf(mx, __shfl_xor(mx, 16));
      mx = fmaxf(mx, __shfl_xor(mx, 32));
      if (!__all(mx <= m_run + 11.5f)) {
        const float mnew = fmaxf(m_run, mx);
        const float corr = exp2f(m_run - mnew);
        m_run = mnew;
        l_run *= corr;
#pragma unroll
        for (int n = 0; n < 4; ++n)
#pragma unroll
          for (int i = 0; i < 4; ++i) acc[n][i] *= corr;
      }
      f32x4 vs = {0.f, 0.f, 0.f, 0.f};
#pragma unroll
      for (int f = 0; f < 8; ++f)
#pragma unroll
        for (int i = 0; i < 4; ++i) {
          const float p = exp2f(s[f][i] - m_run);
          s[f][i] = p;
          vs[i] += p;
        }
      l_run += (vs[0] + vs[1]) + (vs[2] + vs[3]);
    }

    unsigned pk[8][2];
#pragma unroll
    for (int f = 0; f < 8; ++f) {
      pk[f][0] = cvtpk(s[f][0], s[f][1]);
      pk[f][1] = cvtpk(s[f][2], s[f][3]);
    }

#pragma unroll
    for (int st = 0; st < 4; ++st) {
      union { bf16x8 v; unsigned u[4]; } bp;
      bp.u[0] = pk[2 * st][0];
      bp.u[1] = pk[2 * st][1];
      bp.u[2] = pk[2 * st + 1][0];
      bp.u[3] = pk[2 * st + 1][1];
      const int cb = (st * 32 + g * 8) * 2;
      bf16x8 bv[4];
#pragma unroll
      for (int n = 0; n < 4; ++n) {
        const int d = n * 16 + q;
        bv[n] = *(const bf16x8*)(lds_v + d * 256 + (cb ^ ((d & 7) << 4)));
      }
      __builtin_amdgcn_s_setprio(1);
#pragma unroll
      for (int n = 0; n < 4; ++n)
        acc[n] = MFMA16(bv[n], bp.v, acc[n]);
      __builtin_amdgcn_s_setprio(0);
    }
    vcur[0] = vnxt[0];
    vcur[1] = vnxt[1];
  }

  l_run += __shfl_xor(l_run, 16);
  l_run += __shfl_xor(l_run, 32);
  const float rl = 1.f / l_run;

  __syncthreads();
  {
    char* lds_o = asmem;
    const int row = w * 16 + q;
#pragma unroll
    for (int n = 0; n < 4; ++n)
#pragma unroll
      for (int i2 = 0; i2 < 2; ++i2) {
        const unsigned pr = cvtpk(acc[n][2 * i2] * rl, acc[n][2 * i2 + 1] * rl);
        *(unsigned*)(lds_o + row * 144 + n * 32 + g * 8 + i2 * 4) = pr;
      }
  }
  __syncthreads();
  {
    const char* lds_o = asmem;
    const int row2 = tid >> 2;
    const int seg = tid & 3;
    const uint4 v0 = *(const uint4*)(lds_o + row2 * 144 + seg * 32);
    const uint4 v1 = *(const uint4*)(lds_o + row2 * 144 + seg * 32 + 16);
    bf16_t* dst = attn_out + ((size_t)(b * SEQ + qt * 128 + row2)) * H + h * HD + seg * 16;
    *(uint4*)dst = v0;
    *(uint4*)(dst + 8) = v1;
  }
}

// ---------------- launcher ---------------------------------------------------
extern "C" void kernel_launch(void* const* d_in, const int* in_sizes, int n_in,
                              void* d_out, int out_size, void* d_ws, size_t ws_size,
                              hipStream_t stream) {
  const float* x    = (const float*)d_in[0];
  const float* ln1w = (const float*)d_in[3];
  const float* q_w  = (const float*)d_in[4];
  const float* q_b  = (const float*)d_in[5];
  const float* k_w  = (const float*)d_in[6];
  const float* k_b  = (const float*)d_in[7];
  const float* v_w  = (const float*)d_in[8];
  const float* v_b  = (const float*)d_in[9];
  const float* o_w  = (const float*)d_in[10];
  const float* ln2w = (const float*)d_in[11];
  const float* g_w  = (const float*)d_in[12];
  const float* u_w  = (const float*)d_in[13];
  const float* dn_w = (const float*)d_in[14];
  float* out = (float*)d_out;

  char* ws = (char*)d_ws;
  bf16_t* wqkv = (bf16_t*)(ws + 0);         // 1152x896
  bf16_t* wo   = (bf16_t*)(ws + 2064384);   // 896x896
  bf16_t* wgu  = (bf16_t*)(ws + 3670016);   // 9728x896 (interleaved gate/up)
  bf16_t* wd   = (bf16_t*)(ws + 21102592);  // 896x4864
  float*  bqkv = (float*)(ws + 29818880);   // 1152
  bf16_t* hbuf = (bf16_t*)(ws + 29823488);  // 4096x896 (h1, then h2)
  bf16_t* qkv  = (bf16_t*)(ws + 37163520);  // 4096x1152
  bf16_t* attn = (bf16_t*)(ws + 46600704);  // 4096x896
  bf16_t* gu   = (bf16_t*)(ws + 53940736);  // 4096x4864
  // split-K partials (bf16, 2x 4096x896) overlay dead bqkv/hbuf/qkv region
  bf16_t* part = (bf16_t*)(ws + 29818880);  // [29818880, 44498944)

  hipFuncSetAttribute((const void*)gateup_kernel,
                      hipFuncAttributeMaxDynamicSharedMemorySize, 131072);

  cvt_all<<<14560, 256, 0, stream>>>(q_w, k_w, v_w, o_w, g_w, u_w, dn_w,
                                     wqkv, wo, wgu, wd);
  bias_cat_kernel<<<5, 256, 0, stream>>>(q_b, k_b, v_b, bqkv);

  // pre-norm attention
  rmsnorm_kernel<<<4096, 256, 0, stream>>>(x, ln1w, hbuf);
  gemm_bt<64, 0><<<576, 256, 0, stream>>>(hbuf, wqkv, qkv, nullptr, bqkv,
                                          nullptr, 4096, 1152, 896, 896, 896);
  attn_kernel<<<dim3(16, 14, 2), 512, 0, stream>>>(qkv, attn);
  gemm_bt<64, 1><<<448, 256, 0, stream>>>(attn, wo, nullptr, out, nullptr, x,
                                          4096, 896, 896, 896, 896);
  // pre-norm SwiGLU MLP
  rmsnorm_kernel<<<4096, 256, 0, stream>>>(out, ln2w, hbuf);
  gateup_kernel<<<608, 512, 131072, stream>>>(hbuf, wgu, gu);
  // down-proj: split-K=2 bf16 partials + fused reduce(+residual)
  gemm_bt<128, 2><<<448, 256, 0, stream>>>(gu, wd, part, nullptr, nullptr, nullptr,
                                           4096, 896, 2432, 4864, 4864);
  reduce_kernel<<<3584, 256, 0, stream>>>(out, part);
}